// Round 4
// baseline (431.513 us; speedup 1.0000x reference)
//
#include <hip/hip_runtime.h>
#include <math.h>

#define N_NODES 20000
#define N_EDGES 320000
#define N_GRAPHS 64
#define D_IN 1280
#define D_H 512
#define D_FC 1024
#define OUT_DIMS 5000
#define BKT_CAP 64  // max degree capacity (true max ~38 for Poisson(16) over 20k nodes)
#define PSPLIT 8    // pool node-split factor

typedef unsigned short ushort_t;
typedef short bf16x8 __attribute__((ext_vector_type(8)));
typedef float f32x4 __attribute__((ext_vector_type(4)));

__device__ __forceinline__ ushort_t f2b(float x) {
    unsigned u = __float_as_uint(x);
    unsigned r = (u + 0x7FFFu + ((u >> 16) & 1u)) >> 16;  // RNE
    return (ushort_t)r;
}

// packed f32x2 -> bf16x2, RNE (bit-identical to f2b for normal values)
__device__ __forceinline__ unsigned cvt_pk(float lo, float hi) {
    unsigned r;
    asm("v_cvt_pk_bf16_f32 %0, %1, %2" : "=v"(r) : "v"(lo), "v"(hi));
    return r;
}

// raw barrier + counted waits (T3/T4): prefetch DMAs stay in flight across barriers
#define BAR() asm volatile("s_barrier" ::: "memory")
#define WAITVM(n) asm volatile("s_waitcnt vmcnt(" #n ")" ::: "memory")
#define WAITLG() asm volatile("s_waitcnt lgkmcnt(0)" ::: "memory")
#define SCHED0() __builtin_amdgcn_sched_barrier(0)

// async 16B global->LDS DMA: per-lane gptr, wave-uniform LDS base + lane*16
#define GLL16(gp, lp)                                                                  \
    __builtin_amdgcn_global_load_lds((const __attribute__((address_space(1))) void*)(gp), \
                                     (__attribute__((address_space(3))) void*)(lp), 16, 0, 0)

// XCD swizzle for conv GEMMs: grid (32, 20) -> f in [0,640)
// 4 col-tiles of a row-tile share f&7 (same XCD) -> A row-panel L2-resident
#define CONV_SWIZZLE()                                         \
    const int f = blockIdx.y * 32 + blockIdx.x;                \
    const int rt = (f >> 5) * 8 + (f & 7);                     \
    const int ct = (f & 31) >> 3;                              \
    const int rowBase = rt * 128;                              \
    const int colBase = ct * 128;                              \
    if (rowBase >= M) return;

// ============ bf16 MFMA GEMM, counted-vmcnt double-buffered DMA (conv2) ============
// Per-wave vmcnt ledger: ISSUE_TILE = 4 DMA ops. Steady state at loop top:
// in flight = tile k (4, oldest) + tile k+1 (4) -> vmcnt(4) lands tile k, keeps k+1 flying.
__global__ __launch_bounds__(256) void mfma_gemm_db(const ushort_t* __restrict__ A,
                                                    const ushort_t* __restrict__ BT,
                                                    ushort_t* __restrict__ C,
                                                    int M, int N, int K) {
    __shared__ ushort_t lds[4 * 4096];  // As0, As1, Bs0, Bs1 (8 KB each)
    const int t = threadIdx.x;
    const int lane = t & 63, wave = t >> 6;
    const int wrow = (wave >> 1) * 64, wcol = (wave & 1) * 64;
    const int lo = lane & 15, quad = lane >> 4;
    CONV_SWIZZLE();

    const int s0 = t, s1 = t + 256;
    const int r0 = s0 >> 2, r1 = s1 >> 2;
    const int q0 = (s0 & 3) ^ ((r0 >> 1) & 3);
    const int q1 = (s1 & 3) ^ ((r1 >> 1) & 3);
    int ar0 = rowBase + r0; if (ar0 >= M) ar0 = M - 1;
    int ar1 = rowBase + r1; if (ar1 >= M) ar1 = M - 1;
    const ushort_t* pa0 = A + (size_t)ar0 * K + q0 * 8;
    const ushort_t* pa1 = A + (size_t)ar1 * K + q1 * 8;
    const ushort_t* pb0 = BT + (size_t)(colBase + r0) * K + q0 * 8;
    const ushort_t* pb1 = BT + (size_t)(colBase + r1) * K + q1 * 8;

#define ISSUE_TILE(p)                                                  \
    {                                                                  \
        GLL16(pa0, lds + (p) * 4096 + wave * 512);                     \
        GLL16(pa1, lds + (p) * 4096 + 2048 + wave * 512);              \
        GLL16(pb0, lds + 8192 + (p) * 4096 + wave * 512);              \
        GLL16(pb1, lds + 8192 + (p) * 4096 + 2048 + wave * 512);       \
        pa0 += 32; pa1 += 32; pb0 += 32; pb1 += 32;                    \
    }

    const int qs = (quad ^ ((lo >> 1) & 3)) * 8;
    int offA[4], offB[4];
#pragma unroll
    for (int i = 0; i < 4; ++i) offA[i] = (wrow + i * 16 + lo) * 32 + qs;
#pragma unroll
    for (int j = 0; j < 4; ++j) offB[j] = (wcol + j * 16 + lo) * 32 + qs;

    f32x4 acc[4][4] = {};
    const int NK = K >> 5;

    ISSUE_TILE(0);
    if (NK > 1) ISSUE_TILE(1);

    for (int k = 0; k < NK; ++k) {
        if (k + 1 < NK) { WAITVM(4); } else { WAITVM(0); }  // own tile-k DMAs landed
        BAR();                                               // all waves' tile k landed
        const ushort_t* Ab = lds + (k & 1) * 4096;
        const ushort_t* Bb = lds + 8192 + (k & 1) * 4096;
        bf16x8 af[4], bfr[4];
#pragma unroll
        for (int i = 0; i < 4; ++i) af[i] = *(const bf16x8*)&Ab[offA[i]];
#pragma unroll
        for (int j = 0; j < 4; ++j) bfr[j] = *(const bf16x8*)&Bb[offB[j]];
        WAITLG();  // frag ds_reads complete before declaring buf reusable
        BAR();
        if (k + 2 < NK) { ISSUE_TILE(k & 1); }  // flies across next barrier
        SCHED0();
        __builtin_amdgcn_s_setprio(1);
#pragma unroll
        for (int i = 0; i < 4; ++i)
#pragma unroll
            for (int j = 0; j < 4; ++j)
                acc[i][j] = __builtin_amdgcn_mfma_f32_16x16x32_bf16(af[i], bfr[j], acc[i][j], 0, 0, 0);
        __builtin_amdgcn_s_setprio(0);
    }
#undef ISSUE_TILE

#pragma unroll
    for (int i = 0; i < 4; ++i) {
        int row0 = rowBase + wrow + i * 16 + quad * 4;
#pragma unroll
        for (int j = 0; j < 4; ++j) {
            int col = colBase + wcol + j * 16 + lo;
            if (col >= N) continue;
#pragma unroll
            for (int r = 0; r < 4; ++r) {
                int row = row0 + r;
                if (row < M) C[(size_t)row * N + col] = f2b(acc[i][j][r]);
            }
        }
    }
}

// ============ f32-A bf16 MFMA GEMM (conv1), counted-vmcnt ============
// A reg-staged (global f32 -> cvt_pk -> ds_write, XOR-swizzled); B via DMA dbuf.
// Ledger (issue order pinned by SCHED0): prologue [A0:4][B0:2 B1:2] WRITEA(0) [A1:4].
// Top of iter k: outstanding <= {B(k+1):2, A(k+1):4}; vmcnt(6) retires B(k) at k=0,
// no-op later (compiler's va-dependence wait before WRITEA retires older ops).
__global__ __launch_bounds__(256) void mfma_gemm_af32(const float* __restrict__ A,
                                                      const ushort_t* __restrict__ BT,
                                                      ushort_t* __restrict__ C,
                                                      int M, int N, int K) {
    __shared__ ushort_t lds[4 * 4096];  // As0, As1 [0,8192) ; Bs0, Bs1 [8192,16384)
    const int t = threadIdx.x;
    const int lane = t & 63, wave = t >> 6;
    const int wrow = (wave >> 1) * 64, wcol = (wave & 1) * 64;
    const int lo = lane & 15, quad = lane >> 4;
    CONV_SWIZZLE();

    // B DMA mapping (identical to bf16 kernel)
    const int s0 = t, s1 = t + 256;
    const int r0 = s0 >> 2, r1 = s1 >> 2;
    const int q0 = (s0 & 3) ^ ((r0 >> 1) & 3);
    const int q1 = (s1 & 3) ^ ((r1 >> 1) & 3);
    const ushort_t* pb0 = BT + (size_t)(colBase + r0) * K + q0 * 8;
    const ushort_t* pb1 = BT + (size_t)(colBase + r1) * K + q1 * 8;
    ushort_t* ldsB = lds + 8192;

#define ISSUE_B(p)                                              \
    {                                                           \
        GLL16(pb0, ldsB + (p) * 4096 + wave * 512);             \
        GLL16(pb1, ldsB + (p) * 4096 + 2048 + wave * 512);      \
        pb0 += 32; pb1 += 32;                                   \
    }

    // A staging: thread t -> row rA = t>>1, half hA = t&1 (chunks 2hA, 2hA+1)
    const int rA = t >> 1, hA = t & 1;
    int ar = rowBase + rA; if (ar >= M) ar = M - 1;  // clamped rows never stored
    const float* pA = A + (size_t)ar * K + hA * 16;
    const int sw = (rA >> 1) & 3;
    const int wrA0 = rA * 32 + ((2 * hA) ^ sw) * 8;
    const int wrA1 = rA * 32 + ((2 * hA + 1) ^ sw) * 8;
    float4 va0, va1, va2, va3;

#define LOADA()                                  \
    {                                            \
        va0 = *(const float4*)(pA + 0);          \
        va1 = *(const float4*)(pA + 4);          \
        va2 = *(const float4*)(pA + 8);          \
        va3 = *(const float4*)(pA + 12);         \
        pA += 32;                                \
    }
#define WRITEA(p)                                                           \
    {                                                                       \
        uint4 u0, u1;                                                       \
        u0.x = cvt_pk(va0.x, va0.y); u0.y = cvt_pk(va0.z, va0.w);           \
        u0.z = cvt_pk(va1.x, va1.y); u0.w = cvt_pk(va1.z, va1.w);           \
        u1.x = cvt_pk(va2.x, va2.y); u1.y = cvt_pk(va2.z, va2.w);           \
        u1.z = cvt_pk(va3.x, va3.y); u1.w = cvt_pk(va3.z, va3.w);           \
        *(uint4*)&lds[(p) * 4096 + wrA0] = u0;                              \
        *(uint4*)&lds[(p) * 4096 + wrA1] = u1;                              \
    }

    const int qs = (quad ^ ((lo >> 1) & 3)) * 8;
    int offA[4], offB[4];
#pragma unroll
    for (int i = 0; i < 4; ++i) offA[i] = (wrow + i * 16 + lo) * 32 + qs;
#pragma unroll
    for (int j = 0; j < 4; ++j) offB[j] = (wcol + j * 16 + lo) * 32 + qs;

    f32x4 acc[4][4] = {};
    const int NK = K >> 5;  // 40 for D_IN

    LOADA();      // A0: 4 loads (oldest)
    SCHED0();
    ISSUE_B(0);   // B0: 2
    ISSUE_B(1);   // B1: 2
    SCHED0();
    WRITEA(0);    // compiler's own wait retires A0 (keeps B0,B1 in flight)
    SCHED0();
    LOADA();      // A1: 4
    SCHED0();
    WAITLG();     // tile-0 A ds_writes drained before first barrier

    for (int k = 0; k < NK; ++k) {
        WAITVM(6);  // k=0: retires B0 (outstanding B0,B1,A1=8); steady: no-op
        BAR();      // buf(k&1) fully populated for all waves
        const ushort_t* Ab = lds + (k & 1) * 4096;
        const ushort_t* Bb = ldsB + (k & 1) * 4096;
        bf16x8 af[4], bfr[4];
#pragma unroll
        for (int i = 0; i < 4; ++i) af[i] = *(const bf16x8*)&Ab[offA[i]];
#pragma unroll
        for (int j = 0; j < 4; ++j) bfr[j] = *(const bf16x8*)&Bb[offB[j]];
        WAITLG();   // frag reads complete
        BAR();      // buf(k&1) reusable
        if (k + 2 < NK) { ISSUE_B(k & 1); }  // B(k+2): 2
        SCHED0();
        if (k + 1 < NK) {
            WRITEA((k + 1) & 1);  // waits A(k+1) via compiler dep-tracking
            SCHED0();
            if (k + 2 < NK) { LOADA(); }  // A(k+2): 4
            SCHED0();
        }
        __builtin_amdgcn_s_setprio(1);
#pragma unroll
        for (int i = 0; i < 4; ++i)
#pragma unroll
            for (int j = 0; j < 4; ++j)
                acc[i][j] = __builtin_amdgcn_mfma_f32_16x16x32_bf16(af[i], bfr[j], acc[i][j], 0, 0, 0);
        __builtin_amdgcn_s_setprio(0);
        WAITLG();   // WRITEA ds_writes drained before next top barrier
    }
#undef ISSUE_B
#undef LOADA
#undef WRITEA

#pragma unroll
    for (int i = 0; i < 4; ++i) {
        int row0 = rowBase + wrow + i * 16 + quad * 4;
#pragma unroll
        for (int j = 0; j < 4; ++j) {
            int col = colBase + wcol + j * 16 + lo;
            if (col >= N) continue;
#pragma unroll
            for (int r = 0; r < 4; ++r) {
                int row = row0 + r;
                if (row < M) C[(size_t)row * N + col] = f2b(acc[i][j][r]);
            }
        }
    }
}

// ================= fused prep kernel =================
#define PREP_ZB 5
#define PREP_T1 640
#define PREP_T2 256
#define PREP_NBLK (PREP_ZB + PREP_T1 + PREP_T2 + 1)

__global__ __launch_bounds__(256) void prep_all(const float* __restrict__ W1src, ushort_t* __restrict__ w1t,
                                                const float* __restrict__ W2src, ushort_t* __restrict__ w2t,
                                                int* __restrict__ zbase,  // cursor
                                                const int* __restrict__ batch, int* __restrict__ gstart) {
    __shared__ float tile[32][33];
    int b = blockIdx.x;
    const int t = threadIdx.x;

    if (b < PREP_ZB) {  // zero 20000 ints
        int i = b * 256 + t;
        if (i < 1250) {
            int4* p = (int4*)zbase + (size_t)i * 4;
            int4 z = {0, 0, 0, 0};
            p[0] = z; p[1] = z; p[2] = z; p[3] = z;
        }
        return;
    }
    b -= PREP_ZB;

    if (b < PREP_T1 + PREP_T2) {  // tiled transpose + cvt
        const float* W;
        ushort_t* WT;
        int K, N, tb;
        if (b < PREP_T1) { W = W1src; WT = w1t; K = D_IN; N = D_H; tb = b; }
        else             { W = W2src; WT = w2t; K = D_H;  N = D_H; tb = b - PREP_T1; }
        const int ntn = N >> 5;
        const int kt = tb / ntn, nt = tb - kt * ntn;
        const int tx = t & 31, ty = t >> 5;
#pragma unroll
        for (int it = 0; it < 4; ++it) {
            int k = kt * 32 + ty + it * 8;
            tile[ty + it * 8][tx] = W[(size_t)k * N + nt * 32 + tx];
        }
        __syncthreads();
#pragma unroll
        for (int it = 0; it < 4; ++it) {
            int n = nt * 32 + ty + it * 8;
            WT[(size_t)n * K + kt * 32 + tx] = f2b(tile[tx][ty + it * 8]);
        }
        return;
    }

    // graph_bounds
    if (t <= N_GRAPHS) {
        int lo = 0, hi = N_NODES;
        while (lo < hi) {
            int mid = (lo + hi) >> 1;
            if (batch[mid] < t) lo = mid + 1; else hi = mid;
        }
        gstart[t] = lo;
    }
}

// ---------------- bucket CSR (no scan): col[d*64+p] ----------------
__global__ void fill_bucket(const int* __restrict__ src, const int* __restrict__ dst,
                            int* __restrict__ cursor, int* __restrict__ col) {
    int e = blockIdx.x * blockDim.x + threadIdx.x;
    if (e < N_EDGES) {
        int d = dst[e];
        int p = atomicAdd(cursor + d, 1);
        if (p < BKT_CAP) col[(d << 6) + p] = src[e];
    }
}

// dinv = rsqrt(true_degree + 1); cursor holds true degree after fill_bucket
__global__ void compute_dinv(const int* __restrict__ deg, float* __restrict__ dinv) {
    int v = blockIdx.x * blockDim.x + threadIdx.x;
    if (v < N_NODES) dinv[v] = rsqrtf((float)deg[v] + 1.0f);
}

// ---------------- fp32 split-K tiled GEMM (FC head) ----------------
__global__ __launch_bounds__(256) void gemm_splitk(const float* __restrict__ A,
                                                   const float* __restrict__ B,
                                                   float* __restrict__ P,
                                                   int M, int N, int K, int KC) {
    __shared__ float As[16][64];
    __shared__ float Bs[16][64];
    const int t = threadIdx.x;
    const int tx = t & 15, ty = t >> 4;
    const int rowBase = blockIdx.y * 64;
    const int colBase = blockIdx.x * 64;
    const int kbeg = blockIdx.z * KC;
    const int kend = kbeg + KC;
    float acc[4][4] = {};
    for (int k0 = kbeg; k0 < kend; k0 += 16) {
#pragma unroll
        for (int i = 0; i < 4; ++i) {
            int idx = t + i * 256;
            int row = idx >> 4, kk = idx & 15;
            int gr = rowBase + row;
            As[kk][row] = (gr < M) ? A[(size_t)gr * K + k0 + kk] : 0.f;
        }
#pragma unroll
        for (int i = 0; i < 4; ++i) {
            int idx = t + i * 256;
            int kk = idx >> 6, col = idx & 63;
            int gc = colBase + col;
            Bs[kk][col] = (gc < N) ? B[(size_t)(k0 + kk) * N + gc] : 0.f;
        }
        __syncthreads();
#pragma unroll
        for (int kk = 0; kk < 16; ++kk) {
            float a[4], bb[4];
#pragma unroll
            for (int i = 0; i < 4; ++i) a[i] = As[kk][ty * 4 + i];
#pragma unroll
            for (int j = 0; j < 4; ++j) bb[j] = Bs[kk][tx * 4 + j];
#pragma unroll
            for (int i = 0; i < 4; ++i)
#pragma unroll
                for (int j = 0; j < 4; ++j) acc[i][j] = fmaf(a[i], bb[j], acc[i][j]);
        }
        __syncthreads();
    }
    float* Pz = P + (size_t)blockIdx.z * M * N;
#pragma unroll
    for (int i = 0; i < 4; ++i) {
        int gr = rowBase + ty * 4 + i;
        if (gr >= M) continue;
#pragma unroll
        for (int j = 0; j < 4; ++j) {
            int gc = colBase + tx * 4 + j;
            if (gc < N) Pz[(size_t)gr * N + gc] = acc[i][j];
        }
    }
}

__global__ void reduce_bias_relu(const float* __restrict__ P, const float* __restrict__ b,
                                 float* __restrict__ out, int total, int N, int S) {
    int i = blockIdx.x * blockDim.x + threadIdx.x;
    if (i >= total) return;
    float s = 0.f;
    for (int z = 0; z < S; ++z) s += P[(size_t)z * total + i];
    out[i] = fmaxf(s + b[i % N], 0.f);
}

__global__ void reduce_bn_sigmoid(const float* __restrict__ P, const float* __restrict__ b2,
                                  const float* __restrict__ gamma, const float* __restrict__ beta,
                                  float* __restrict__ out, int S) {
    int i = blockIdx.x * blockDim.x + threadIdx.x;
    if (i >= N_GRAPHS * OUT_DIMS) return;
    int c = i % OUT_DIMS;
    float s = 0.f;
    for (int z = 0; z < S; ++z) s += P[(size_t)z * N_GRAPHS * OUT_DIMS + i];
    const float sc = 0.9999950000374997f;  // 1/sqrt(1+1e-5)
    float zz = (s + b2[c]) * (gamma[c] * sc) + beta[c];
    out[i] = 1.f / (1.f + expf(-zz));
}

// ---------------- bf16 gather-aggregate ----------------
__device__ __forceinline__ void bf8_fma(uint4 v, float c, float* acc) {
    unsigned a[4] = {v.x, v.y, v.z, v.w};
#pragma unroll
    for (int i = 0; i < 4; ++i) {
        float lo = __uint_as_float(a[i] << 16);
        float hi = __uint_as_float(a[i] & 0xFFFF0000u);
        acc[2 * i]     = fmaf(lo, c, acc[2 * i]);
        acc[2 * i + 1] = fmaf(hi, c, acc[2 * i + 1]);
    }
}

__device__ __forceinline__ void agg_node_bf16(const ushort_t* __restrict__ H,
                                              const int* __restrict__ deg,
                                              const int* __restrict__ col,
                                              const float* __restrict__ dinv,
                                              const float* __restrict__ bias,
                                              int v, int f, float* r) {
    const int beg = v << 6;
    int d = deg[v]; if (d > BKT_CAP) d = BKT_CAP;
    const int end = beg + d;
    const float dv = dinv[v];
    float acc[8] = {};
    int j = beg;
    for (; j + 7 < end; j += 8) {
        int s[8];
#pragma unroll
        for (int u = 0; u < 8; ++u) s[u] = col[j + u];
        float c[8];
#pragma unroll
        for (int u = 0; u < 8; ++u) c[u] = dinv[s[u]] * dv;
        uint4 h[8];
#pragma unroll
        for (int u = 0; u < 8; ++u) h[u] = *(const uint4*)(H + (size_t)s[u] * D_H + f);
#pragma unroll
        for (int u = 0; u < 8; ++u) bf8_fma(h[u], c[u], acc);
    }
    for (; j + 3 < end; j += 4) {
        int s0 = col[j], s1 = col[j + 1], s2 = col[j + 2], s3 = col[j + 3];
        float c0 = dinv[s0] * dv, c1 = dinv[s1] * dv;
        float c2 = dinv[s2] * dv, c3 = dinv[s3] * dv;
        uint4 h0 = *(const uint4*)(H + (size_t)s0 * D_H + f);
        uint4 h1 = *(const uint4*)(H + (size_t)s1 * D_H + f);
        uint4 h2 = *(const uint4*)(H + (size_t)s2 * D_H + f);
        uint4 h3 = *(const uint4*)(H + (size_t)s3 * D_H + f);
        bf8_fma(h0, c0, acc);
        bf8_fma(h1, c1, acc);
        bf8_fma(h2, c2, acc);
        bf8_fma(h3, c3, acc);
    }
    for (; j < end; ++j) {
        int s0 = col[j];
        float c0 = dinv[s0] * dv;
        uint4 h0 = *(const uint4*)(H + (size_t)s0 * D_H + f);
        bf8_fma(h0, c0, acc);
    }
    uint4 hv = *(const uint4*)(H + (size_t)v * D_H + f);
    bf8_fma(hv, dv * dv, acc);  // self-loop
    float4 b0 = *(const float4*)(bias + f);
    float4 b1 = *(const float4*)(bias + f + 4);
    r[0] = fmaxf(acc[0] + b0.x, 0.f);
    r[1] = fmaxf(acc[1] + b0.y, 0.f);
    r[2] = fmaxf(acc[2] + b0.z, 0.f);
    r[3] = fmaxf(acc[3] + b0.w, 0.f);
    r[4] = fmaxf(acc[4] + b1.x, 0.f);
    r[5] = fmaxf(acc[5] + b1.y, 0.f);
    r[6] = fmaxf(acc[6] + b1.z, 0.f);
    r[7] = fmaxf(acc[7] + b1.w, 0.f);
}

// 4 nodes per block (one per wave)
__global__ __launch_bounds__(256) void gather_agg_relu_bf16(const ushort_t* __restrict__ H,
                                                            const int* __restrict__ deg,
                                                            const int* __restrict__ col,
                                                            const float* __restrict__ dinv,
                                                            const float* __restrict__ bias,
                                                            ushort_t* __restrict__ out) {
    const int v = blockIdx.x * 4 + (threadIdx.x >> 6);
    const int f = (threadIdx.x & 63) * 8;
    float r[8];
    agg_node_bf16(H, deg, col, dinv, bias, v, f, r);
    ushort_t o[8];
#pragma unroll
    for (int i = 0; i < 8; ++i) o[i] = f2b(r[i]);
    *(uint4*)(out + (size_t)v * D_H + f) = *(uint4*)o;
}

// ---------------- segment max pool: node-split partial + reduce ----------------
__global__ __launch_bounds__(256) void pool_max_partial(const ushort_t* __restrict__ h2,
                                                        const int* __restrict__ gstart,
                                                        float* __restrict__ pbuf) {
    const int g = blockIdx.x;
    const int s = blockIdx.y;
    const int f = threadIdx.x * 2;
    const int beg = gstart[g], end = gstart[g + 1];
    const int len = end - beg;
    const int chunk = (len + PSPLIT - 1) / PSPLIT;
    int lo = beg + s * chunk;
    int hi = lo + chunk; if (hi > end) hi = end;
    float m0 = -INFINITY, m1 = -INFINITY;
    int v = lo;
    for (; v + 3 < hi; v += 4) {
        unsigned u0 = *(const unsigned*)(h2 + (size_t)(v + 0) * D_H + f);
        unsigned u1 = *(const unsigned*)(h2 + (size_t)(v + 1) * D_H + f);
        unsigned u2 = *(const unsigned*)(h2 + (size_t)(v + 2) * D_H + f);
        unsigned u3 = *(const unsigned*)(h2 + (size_t)(v + 3) * D_H + f);
        m0 = fmaxf(m0, fmaxf(fmaxf(__uint_as_float(u0 << 16), __uint_as_float(u1 << 16)),
                             fmaxf(__uint_as_float(u2 << 16), __uint_as_float(u3 << 16))));
        m1 = fmaxf(m1, fmaxf(fmaxf(__uint_as_float(u0 & 0xFFFF0000u), __uint_as_float(u1 & 0xFFFF0000u)),
                             fmaxf(__uint_as_float(u2 & 0xFFFF0000u), __uint_as_float(u3 & 0xFFFF0000u))));
    }
    for (; v < hi; ++v) {
        unsigned u = *(const unsigned*)(h2 + (size_t)v * D_H + f);
        m0 = fmaxf(m0, __uint_as_float(u << 16));
        m1 = fmaxf(m1, __uint_as_float(u & 0xFFFF0000u));
    }
    float* p = pbuf + ((size_t)s * N_GRAPHS + g) * D_H + f;
    p[0] = m0;
    p[1] = m1;
}

__global__ void pool_max_final(const float* __restrict__ pbuf, float* __restrict__ gbuf) {
    int i = blockIdx.x * blockDim.x + threadIdx.x;
    if (i >= N_GRAPHS * D_H) return;
    float m = -INFINITY;
#pragma unroll
    for (int s = 0; s < PSPLIT; ++s) m = fmaxf(m, pbuf[(size_t)s * N_GRAPHS * D_H + i]);
    gbuf[i] = m;
}

extern "C" void kernel_launch(void* const* d_in, const int* in_sizes, int n_in,
                              void* d_out, int out_size, void* d_ws, size_t ws_size,
                              hipStream_t stream) {
    const float* x     = (const float*)d_in[0];
    const int*   ei    = (const int*)d_in[1];
    const int*   batch = (const int*)d_in[2];
    const float* Wg1   = (const float*)d_in[3];
    const float* bg1   = (const float*)d_in[4];
    const float* Wg2   = (const float*)d_in[5];
    const float* bg2   = (const float*)d_in[6];
    const float* W1    = (const float*)d_in[7];
    const float* b1    = (const float*)d_in[8];
    const float* W2    = (const float*)d_in[9];
    const float* b2    = (const float*)d_in[10];
    const float* gamma = (const float*)d_in[11];
    const float* beta  = (const float*)d_in[12];
    const int* src = ei;
    const int* dst = ei + N_EDGES;
    float* out = (float*)d_out;

    const int S1 = 8;  // fc1 K-split
    const int S2 = 8;  // fc2 K-split

    // workspace layout (16B-aligned)
    ushort_t* hpre   = (ushort_t*)d_ws;                        // [N_NODES, D_H] bf16
    ushort_t* h1b    = hpre + (size_t)N_NODES * D_H;           // [N_NODES, D_H] bf16
    ushort_t* w1t    = h1b + (size_t)N_NODES * D_H;            // [D_H, D_IN] bf16
    ushort_t* w2t    = w1t + (size_t)D_H * D_IN;               // [D_H, D_H] bf16
    float*    dinv   = (float*)(w2t + (size_t)D_H * D_H);      // [N_NODES]
    float*    gbuf   = dinv + N_NODES;                         // [N_GRAPHS, D_H]
    float*    pbuf   = gbuf + N_GRAPHS * D_H;                  // [PSPLIT, N_GRAPHS, D_H]
    float*    fc1o   = pbuf + (size_t)PSPLIT * N_GRAPHS * D_H; // [N_GRAPHS, D_FC]
    float*    part1  = fc1o + N_GRAPHS * D_FC;                 // [S1, 64, D_FC]
    float*    part2  = part1 + (size_t)S1 * N_GRAPHS * D_FC;   // [S2, 64, OUT_DIMS]
    int*      cursor = (int*)(part2 + (size_t)S2 * N_GRAPHS * OUT_DIMS);  // [N_NODES] -> degree
    int*      colbkt = cursor + N_NODES;                       // [N_NODES * BKT_CAP]
    int*      gstart = colbkt + (size_t)N_NODES * BKT_CAP;     // [N_GRAPHS+1]

    // ---- fused prep: zero cursor + W1^T + W2^T + graph bounds ----
    prep_all<<<PREP_NBLK, 256, 0, stream>>>(Wg1, w1t, Wg2, w2t, cursor, batch, gstart);

    // ---- bucket adjacency build ----
    fill_bucket<<<(N_EDGES + 255) / 256, 256, 0, stream>>>(src, dst, cursor, colbkt);
    compute_dinv<<<(N_NODES + 255) / 256, 256, 0, stream>>>(cursor, dinv);

    dim3 gconv(32, 20);  // 640 slots, 628 active (157 row-tiles x 4 col-tiles)

    // conv1: hpre = bf16(x @ Wg1), A consumed as f32 in-kernel ; gather+relu -> h1b
    mfma_gemm_af32<<<gconv, 256, 0, stream>>>(x, w1t, hpre, N_NODES, D_H, D_IN);
    gather_agg_relu_bf16<<<N_NODES / 4, 256, 0, stream>>>(hpre, cursor, colbkt, dinv, bg1, h1b);

    // conv2: hpre = bf16(h1b @ Wg2) ; gather+relu -> h2 (reuse h1b) ; pool
    mfma_gemm_db<<<gconv, 256, 0, stream>>>(h1b, w2t, hpre, N_NODES, D_H, D_H);
    gather_agg_relu_bf16<<<N_NODES / 4, 256, 0, stream>>>(hpre, cursor, colbkt, dinv, bg2, h1b);
    pool_max_partial<<<dim3(N_GRAPHS, PSPLIT), 256, 0, stream>>>(h1b, gstart, pbuf);
    pool_max_final<<<(N_GRAPHS * D_H + 255) / 256, 256, 0, stream>>>(pbuf, gbuf);

    // fc1: [64,512]@[512,1024] split-K=8 -> part1 ; reduce + b1 + relu -> fc1o
    dim3 gfc1((D_FC + 63) / 64, 1, S1);
    gemm_splitk<<<gfc1, 256, 0, stream>>>(gbuf, W1, part1, N_GRAPHS, D_FC, D_H, D_H / S1);
    reduce_bias_relu<<<(N_GRAPHS * D_FC + 255) / 256, 256, 0, stream>>>(
        part1, b1, fc1o, N_GRAPHS * D_FC, D_FC, S1);

    // fc2: [64,1024]@[1024,5000] split-K=8 -> part2 ; reduce + BN + sigmoid -> out
    dim3 gfc2((OUT_DIMS + 63) / 64, 1, S2);
    gemm_splitk<<<gfc2, 256, 0, stream>>>(fc1o, W2, part2, N_GRAPHS, OUT_DIMS, D_FC, D_FC / S2);
    reduce_bn_sigmoid<<<(N_GRAPHS * OUT_DIMS + 255) / 256, 256, 0, stream>>>(
        part2, b2, gamma, beta, out, S2);
}

// Round 5
// 427.800 us; speedup vs baseline: 1.0087x; 1.0087x over previous
//
#include <hip/hip_runtime.h>
#include <math.h>

#define N_NODES 20000
#define N_EDGES 320000
#define N_GRAPHS 64
#define D_IN 1280
#define D_H 512
#define D_FC 1024
#define OUT_DIMS 5000
#define BKT_CAP 64  // max degree capacity (true max ~38 for Poisson(16) over 20k nodes)
#define PSPLIT 8    // pool node-split factor

typedef unsigned short ushort_t;
typedef short bf16x8 __attribute__((ext_vector_type(8)));
typedef float f32x4 __attribute__((ext_vector_type(4)));

__device__ __forceinline__ ushort_t f2b(float x) {
    unsigned u = __float_as_uint(x);
    unsigned r = (u + 0x7FFFu + ((u >> 16) & 1u)) >> 16;  // RNE
    return (ushort_t)r;
}

// packed f32x2 -> bf16x2, RNE (bit-identical to f2b for normal values)
__device__ __forceinline__ unsigned cvt_pk(float lo, float hi) {
    unsigned r;
    asm("v_cvt_pk_bf16_f32 %0, %1, %2" : "=v"(r) : "v"(lo), "v"(hi));
    return r;
}

// raw barrier + counted waits (T3/T4): prefetch DMAs stay in flight across barriers
#define BAR() asm volatile("s_barrier" ::: "memory")
#define WAITVM(n) asm volatile("s_waitcnt vmcnt(" #n ")" ::: "memory")
#define WAITLG() asm volatile("s_waitcnt lgkmcnt(0)" ::: "memory")
#define SCHED0() __builtin_amdgcn_sched_barrier(0)

// async 16B global->LDS DMA: per-lane gptr, wave-uniform LDS base + lane*16
#define GLL16(gp, lp)                                                                  \
    __builtin_amdgcn_global_load_lds((const __attribute__((address_space(1))) void*)(gp), \
                                     (__attribute__((address_space(3))) void*)(lp), 16, 0, 0)

// XCD swizzle for conv GEMMs: grid (32, 20) -> f in [0,640)
// 4 col-tiles of a row-tile share f&7 (same XCD) -> A row-panel L2-resident
#define CONV_SWIZZLE()                                         \
    const int f = blockIdx.y * 32 + blockIdx.x;                \
    const int rt = (f >> 5) * 8 + (f & 7);                     \
    const int ct = (f & 31) >> 3;                              \
    const int rowBase = rt * 128;                              \
    const int colBase = ct * 128;                              \
    if (rowBase >= M) return;

// ============ bf16 MFMA GEMM, counted-vmcnt double-buffered DMA (conv2) ============
// Per-wave vmcnt ledger: ISSUE_TILE = 4 DMA ops. Steady state at loop top:
// in flight = tile k (4, oldest) + tile k+1 (4) -> vmcnt(4) lands tile k, keeps k+1 flying.
__global__ __launch_bounds__(256) void mfma_gemm_db(const ushort_t* __restrict__ A,
                                                    const ushort_t* __restrict__ BT,
                                                    ushort_t* __restrict__ C,
                                                    int M, int N, int K) {
    __shared__ ushort_t lds[4 * 4096];  // As0, As1, Bs0, Bs1 (8 KB each)
    const int t = threadIdx.x;
    const int lane = t & 63, wave = t >> 6;
    const int wrow = (wave >> 1) * 64, wcol = (wave & 1) * 64;
    const int lo = lane & 15, quad = lane >> 4;
    CONV_SWIZZLE();

    const int s0 = t, s1 = t + 256;
    const int r0 = s0 >> 2, r1 = s1 >> 2;
    const int q0 = (s0 & 3) ^ ((r0 >> 1) & 3);
    const int q1 = (s1 & 3) ^ ((r1 >> 1) & 3);
    int ar0 = rowBase + r0; if (ar0 >= M) ar0 = M - 1;
    int ar1 = rowBase + r1; if (ar1 >= M) ar1 = M - 1;
    const ushort_t* pa0 = A + (size_t)ar0 * K + q0 * 8;
    const ushort_t* pa1 = A + (size_t)ar1 * K + q1 * 8;
    const ushort_t* pb0 = BT + (size_t)(colBase + r0) * K + q0 * 8;
    const ushort_t* pb1 = BT + (size_t)(colBase + r1) * K + q1 * 8;

#define ISSUE_TILE(p)                                                  \
    {                                                                  \
        GLL16(pa0, lds + (p) * 4096 + wave * 512);                     \
        GLL16(pa1, lds + (p) * 4096 + 2048 + wave * 512);              \
        GLL16(pb0, lds + 8192 + (p) * 4096 + wave * 512);              \
        GLL16(pb1, lds + 8192 + (p) * 4096 + 2048 + wave * 512);       \
        pa0 += 32; pa1 += 32; pb0 += 32; pb1 += 32;                    \
    }

    const int qs = (quad ^ ((lo >> 1) & 3)) * 8;
    int offA[4], offB[4];
#pragma unroll
    for (int i = 0; i < 4; ++i) offA[i] = (wrow + i * 16 + lo) * 32 + qs;
#pragma unroll
    for (int j = 0; j < 4; ++j) offB[j] = (wcol + j * 16 + lo) * 32 + qs;

    f32x4 acc[4][4] = {};
    const int NK = K >> 5;

    ISSUE_TILE(0);
    if (NK > 1) ISSUE_TILE(1);

    for (int k = 0; k < NK; ++k) {
        if (k + 1 < NK) { WAITVM(4); } else { WAITVM(0); }  // own tile-k DMAs landed
        BAR();                                               // all waves' tile k landed
        const ushort_t* Ab = lds + (k & 1) * 4096;
        const ushort_t* Bb = lds + 8192 + (k & 1) * 4096;
        bf16x8 af[4], bfr[4];
#pragma unroll
        for (int i = 0; i < 4; ++i) af[i] = *(const bf16x8*)&Ab[offA[i]];
#pragma unroll
        for (int j = 0; j < 4; ++j) bfr[j] = *(const bf16x8*)&Bb[offB[j]];
        WAITLG();  // frag ds_reads complete before declaring buf reusable
        BAR();
        if (k + 2 < NK) { ISSUE_TILE(k & 1); }  // flies across next barrier
        SCHED0();
        __builtin_amdgcn_s_setprio(1);
#pragma unroll
        for (int i = 0; i < 4; ++i)
#pragma unroll
            for (int j = 0; j < 4; ++j)
                acc[i][j] = __builtin_amdgcn_mfma_f32_16x16x32_bf16(af[i], bfr[j], acc[i][j], 0, 0, 0);
        __builtin_amdgcn_s_setprio(0);
    }
#undef ISSUE_TILE

#pragma unroll
    for (int i = 0; i < 4; ++i) {
        int row0 = rowBase + wrow + i * 16 + quad * 4;
#pragma unroll
        for (int j = 0; j < 4; ++j) {
            int col = colBase + wcol + j * 16 + lo;
            if (col >= N) continue;
#pragma unroll
            for (int r = 0; r < 4; ++r) {
                int row = row0 + r;
                if (row < M) C[(size_t)row * N + col] = f2b(acc[i][j][r]);
            }
        }
    }
}

// ============ f32-A bf16 MFMA GEMM (conv1), 2-deep A-register pipeline ============
// A(j) lives in reg-set (j&1); WRITEA(k+1) at iter k consumes the set loaded at
// iter k-2 -> 2 full iterations of flight on the A loads. B DMA depth also 2 iters.
// Chronological ledger per body k (steady): top outstanding = [B(k):2, A(k+1):4,
// B(k+1):2, A(k+2):4] -> WAITVM(10) lands B(k) only. WRITEA(k+1) waits A(k+1)
// (oldest after top) -> vmcnt<=8 keeps B(k+1), A(k+2), B(k+2) flying.
// Tail: k=NK-2 -> WAITVM(6); k=NK-1 -> WAITVM(0). NK must be EVEN (conv1: 40).
__global__ __launch_bounds__(256) void mfma_gemm_af32(const float* __restrict__ A,
                                                      const ushort_t* __restrict__ BT,
                                                      ushort_t* __restrict__ C,
                                                      int M, int N, int K) {
    __shared__ ushort_t lds[4 * 4096];  // As0, As1 [0,8192) ; Bs0, Bs1 [8192,16384)
    const int t = threadIdx.x;
    const int lane = t & 63, wave = t >> 6;
    const int wrow = (wave >> 1) * 64, wcol = (wave & 1) * 64;
    const int lo = lane & 15, quad = lane >> 4;
    CONV_SWIZZLE();

    // B DMA mapping (identical to bf16 kernel)
    const int s0 = t, s1 = t + 256;
    const int r0 = s0 >> 2, r1 = s1 >> 2;
    const int q0 = (s0 & 3) ^ ((r0 >> 1) & 3);
    const int q1 = (s1 & 3) ^ ((r1 >> 1) & 3);
    const ushort_t* pb0 = BT + (size_t)(colBase + r0) * K + q0 * 8;
    const ushort_t* pb1 = BT + (size_t)(colBase + r1) * K + q1 * 8;
    ushort_t* ldsB = lds + 8192;

#define ISSUE_B(p)                                              \
    {                                                           \
        GLL16(pb0, ldsB + (p) * 4096 + wave * 512);             \
        GLL16(pb1, ldsB + (p) * 4096 + 2048 + wave * 512);      \
        pb0 += 32; pb1 += 32;                                   \
    }

    // A staging: thread t -> row rA = t>>1, half hA = t&1 (chunks 2hA, 2hA+1)
    const int rA = t >> 1, hA = t & 1;
    int ar = rowBase + rA; if (ar >= M) ar = M - 1;  // clamped rows never stored
    const float* pA = A + (size_t)ar * K + hA * 16;
    const int sw = (rA >> 1) & 3;
    const int wrA0 = rA * 32 + ((2 * hA) ^ sw) * 8;
    const int wrA1 = rA * 32 + ((2 * hA + 1) ^ sw) * 8;

    // two named A-register sets (rule #20: static indexing only)
    float4 vA0_0, vA0_1, vA0_2, vA0_3;  // set 0 (tiles j with j&1==0)
    float4 vA1_0, vA1_1, vA1_2, vA1_3;  // set 1 (tiles j with j&1==1)

#define LOADA(S)                                     \
    {                                                \
        vA##S##_0 = *(const float4*)(pA + 0);        \
        vA##S##_1 = *(const float4*)(pA + 4);        \
        vA##S##_2 = *(const float4*)(pA + 8);        \
        vA##S##_3 = *(const float4*)(pA + 12);       \
        pA += 32;                                    \
    }
#define WRITEA(S, p)                                                                    \
    {                                                                                   \
        uint4 u0, u1;                                                                   \
        u0.x = cvt_pk(vA##S##_0.x, vA##S##_0.y); u0.y = cvt_pk(vA##S##_0.z, vA##S##_0.w); \
        u0.z = cvt_pk(vA##S##_1.x, vA##S##_1.y); u0.w = cvt_pk(vA##S##_1.z, vA##S##_1.w); \
        u1.x = cvt_pk(vA##S##_2.x, vA##S##_2.y); u1.y = cvt_pk(vA##S##_2.z, vA##S##_2.w); \
        u1.z = cvt_pk(vA##S##_3.x, vA##S##_3.y); u1.w = cvt_pk(vA##S##_3.z, vA##S##_3.w); \
        *(uint4*)&lds[(p) * 4096 + wrA0] = u0;                                          \
        *(uint4*)&lds[(p) * 4096 + wrA1] = u1;                                          \
    }

    const int qs = (quad ^ ((lo >> 1) & 3)) * 8;
    int offA[4], offB[4];
#pragma unroll
    for (int i = 0; i < 4; ++i) offA[i] = (wrow + i * 16 + lo) * 32 + qs;
#pragma unroll
    for (int j = 0; j < 4; ++j) offB[j] = (wcol + j * 16 + lo) * 32 + qs;

    f32x4 acc[4][4] = {};
    const int NK = K >> 5;  // 40 for D_IN (even)

    // prologue (issue order pinned): A0:4, B0:2, B1:2, A1:4, WRITEA(A0), A2:4
    LOADA(0);             // A0 -> set0 (oldest)
    SCHED0();
    ISSUE_B(0);           // B0: 2
    ISSUE_B(1);           // B1: 2
    SCHED0();
    LOADA(1);             // A1 -> set1
    SCHED0();
    WRITEA(0, 0);         // waits A0 only (vmcnt<=8 keeps B0,B1,A1)
    SCHED0();
    LOADA(0);             // A2 -> set0
    SCHED0();
    WAITLG();             // tile-0 A ds_writes drained before first barrier

    // body: BUF = k&1 (literal), S = (k+1)&1 (literal) — WRITEA(k+1) from set S,
    // LOADA(k+3) into set S (k+3 ≡ k+1 mod 2).
#define AF32_BODY(kv, BUF, S)                                                          \
    {                                                                                  \
        const int k_ = (kv);                                                           \
        if (k_ + 2 < NK) { WAITVM(10); }                                               \
        else if (k_ + 1 < NK) { WAITVM(6); }                                           \
        else { WAITVM(0); }                                                            \
        BAR();                                                                         \
        const ushort_t* Ab = lds + (BUF) * 4096;                                       \
        const ushort_t* Bb = ldsB + (BUF) * 4096;                                      \
        bf16x8 af[4], bfr[4];                                                          \
        _Pragma("unroll") for (int i = 0; i < 4; ++i) af[i] = *(const bf16x8*)&Ab[offA[i]]; \
        _Pragma("unroll") for (int j = 0; j < 4; ++j) bfr[j] = *(const bf16x8*)&Bb[offB[j]]; \
        WAITLG();                                                                      \
        BAR();                                                                         \
        if (k_ + 2 < NK) { ISSUE_B(BUF); }                                             \
        SCHED0();                                                                      \
        if (k_ + 1 < NK) {                                                             \
            WRITEA(S, (BUF) ^ 1);                                                      \
            SCHED0();                                                                  \
            if (k_ + 3 < NK) { LOADA(S); }                                             \
            SCHED0();                                                                  \
        }                                                                              \
        __builtin_amdgcn_s_setprio(1);                                                 \
        _Pragma("unroll") for (int i = 0; i < 4; ++i)                                  \
            _Pragma("unroll") for (int j = 0; j < 4; ++j)                              \
                acc[i][j] = __builtin_amdgcn_mfma_f32_16x16x32_bf16(af[i], bfr[j], acc[i][j], 0, 0, 0); \
        __builtin_amdgcn_s_setprio(0);                                                 \
        WAITLG();                                                                      \
    }

    for (int kk = 0; kk < NK; kk += 2) {
        AF32_BODY(kk, 0, 1);
        AF32_BODY(kk + 1, 1, 0);
    }
#undef AF32_BODY
#undef ISSUE_B
#undef LOADA
#undef WRITEA

#pragma unroll
    for (int i = 0; i < 4; ++i) {
        int row0 = rowBase + wrow + i * 16 + quad * 4;
#pragma unroll
        for (int j = 0; j < 4; ++j) {
            int col = colBase + wcol + j * 16 + lo;
            if (col >= N) continue;
#pragma unroll
            for (int r = 0; r < 4; ++r) {
                int row = row0 + r;
                if (row < M) C[(size_t)row * N + col] = f2b(acc[i][j][r]);
            }
        }
    }
}

// ================= fused prep kernel =================
#define PREP_ZB 5
#define PREP_T1 640
#define PREP_T2 256
#define PREP_NBLK (PREP_ZB + PREP_T1 + PREP_T2 + 1)

__global__ __launch_bounds__(256) void prep_all(const float* __restrict__ W1src, ushort_t* __restrict__ w1t,
                                                const float* __restrict__ W2src, ushort_t* __restrict__ w2t,
                                                int* __restrict__ zbase,  // cursor
                                                const int* __restrict__ batch, int* __restrict__ gstart) {
    __shared__ float tile[32][33];
    int b = blockIdx.x;
    const int t = threadIdx.x;

    if (b < PREP_ZB) {  // zero 20000 ints
        int i = b * 256 + t;
        if (i < 1250) {
            int4* p = (int4*)zbase + (size_t)i * 4;
            int4 z = {0, 0, 0, 0};
            p[0] = z; p[1] = z; p[2] = z; p[3] = z;
        }
        return;
    }
    b -= PREP_ZB;

    if (b < PREP_T1 + PREP_T2) {  // tiled transpose + cvt
        const float* W;
        ushort_t* WT;
        int K, N, tb;
        if (b < PREP_T1) { W = W1src; WT = w1t; K = D_IN; N = D_H; tb = b; }
        else             { W = W2src; WT = w2t; K = D_H;  N = D_H; tb = b - PREP_T1; }
        const int ntn = N >> 5;
        const int kt = tb / ntn, nt = tb - kt * ntn;
        const int tx = t & 31, ty = t >> 5;
#pragma unroll
        for (int it = 0; it < 4; ++it) {
            int k = kt * 32 + ty + it * 8;
            tile[ty + it * 8][tx] = W[(size_t)k * N + nt * 32 + tx];
        }
        __syncthreads();
#pragma unroll
        for (int it = 0; it < 4; ++it) {
            int n = nt * 32 + ty + it * 8;
            WT[(size_t)n * K + kt * 32 + tx] = f2b(tile[tx][ty + it * 8]);
        }
        return;
    }

    // graph_bounds
    if (t <= N_GRAPHS) {
        int lo = 0, hi = N_NODES;
        while (lo < hi) {
            int mid = (lo + hi) >> 1;
            if (batch[mid] < t) lo = mid + 1; else hi = mid;
        }
        gstart[t] = lo;
    }
}

// ---------------- bucket CSR (no scan): col[d*64+p] ----------------
__global__ void fill_bucket(const int* __restrict__ src, const int* __restrict__ dst,
                            int* __restrict__ cursor, int* __restrict__ col) {
    int e = blockIdx.x * blockDim.x + threadIdx.x;
    if (e < N_EDGES) {
        int d = dst[e];
        int p = atomicAdd(cursor + d, 1);
        if (p < BKT_CAP) col[(d << 6) + p] = src[e];
    }
}

// dinv = rsqrt(true_degree + 1); cursor holds true degree after fill_bucket
__global__ void compute_dinv(const int* __restrict__ deg, float* __restrict__ dinv) {
    int v = blockIdx.x * blockDim.x + threadIdx.x;
    if (v < N_NODES) dinv[v] = rsqrtf((float)deg[v] + 1.0f);
}

// ---------------- fp32 split-K tiled GEMM (FC head) ----------------
__global__ __launch_bounds__(256) void gemm_splitk(const float* __restrict__ A,
                                                   const float* __restrict__ B,
                                                   float* __restrict__ P,
                                                   int M, int N, int K, int KC) {
    __shared__ float As[16][64];
    __shared__ float Bs[16][64];
    const int t = threadIdx.x;
    const int tx = t & 15, ty = t >> 4;
    const int rowBase = blockIdx.y * 64;
    const int colBase = blockIdx.x * 64;
    const int kbeg = blockIdx.z * KC;
    const int kend = kbeg + KC;
    float acc[4][4] = {};
    for (int k0 = kbeg; k0 < kend; k0 += 16) {
#pragma unroll
        for (int i = 0; i < 4; ++i) {
            int idx = t + i * 256;
            int row = idx >> 4, kk = idx & 15;
            int gr = rowBase + row;
            As[kk][row] = (gr < M) ? A[(size_t)gr * K + k0 + kk] : 0.f;
        }
#pragma unroll
        for (int i = 0; i < 4; ++i) {
            int idx = t + i * 256;
            int kk = idx >> 6, col = idx & 63;
            int gc = colBase + col;
            Bs[kk][col] = (gc < N) ? B[(size_t)(k0 + kk) * N + gc] : 0.f;
        }
        __syncthreads();
#pragma unroll
        for (int kk = 0; kk < 16; ++kk) {
            float a[4], bb[4];
#pragma unroll
            for (int i = 0; i < 4; ++i) a[i] = As[kk][ty * 4 + i];
#pragma unroll
            for (int j = 0; j < 4; ++j) bb[j] = Bs[kk][tx * 4 + j];
#pragma unroll
            for (int i = 0; i < 4; ++i)
#pragma unroll
                for (int j = 0; j < 4; ++j) acc[i][j] = fmaf(a[i], bb[j], acc[i][j]);
        }
        __syncthreads();
    }
    float* Pz = P + (size_t)blockIdx.z * M * N;
#pragma unroll
    for (int i = 0; i < 4; ++i) {
        int gr = rowBase + ty * 4 + i;
        if (gr >= M) continue;
#pragma unroll
        for (int j = 0; j < 4; ++j) {
            int gc = colBase + tx * 4 + j;
            if (gc < N) Pz[(size_t)gr * N + gc] = acc[i][j];
        }
    }
}

__global__ void reduce_bias_relu(const float* __restrict__ P, const float* __restrict__ b,
                                 float* __restrict__ out, int total, int N, int S) {
    int i = blockIdx.x * blockDim.x + threadIdx.x;
    if (i >= total) return;
    float s = 0.f;
    for (int z = 0; z < S; ++z) s += P[(size_t)z * total + i];
    out[i] = fmaxf(s + b[i % N], 0.f);
}

__global__ void reduce_bn_sigmoid(const float* __restrict__ P, const float* __restrict__ b2,
                                  const float* __restrict__ gamma, const float* __restrict__ beta,
                                  float* __restrict__ out, int S) {
    int i = blockIdx.x * blockDim.x + threadIdx.x;
    if (i >= N_GRAPHS * OUT_DIMS) return;
    int c = i % OUT_DIMS;
    float s = 0.f;
    for (int z = 0; z < S; ++z) s += P[(size_t)z * N_GRAPHS * OUT_DIMS + i];
    const float sc = 0.9999950000374997f;  // 1/sqrt(1+1e-5)
    float zz = (s + b2[c]) * (gamma[c] * sc) + beta[c];
    out[i] = 1.f / (1.f + expf(-zz));
}

// ---------------- bf16 gather-aggregate ----------------
__device__ __forceinline__ void bf8_fma(uint4 v, float c, float* acc) {
    unsigned a[4] = {v.x, v.y, v.z, v.w};
#pragma unroll
    for (int i = 0; i < 4; ++i) {
        float lo = __uint_as_float(a[i] << 16);
        float hi = __uint_as_float(a[i] & 0xFFFF0000u);
        acc[2 * i]     = fmaf(lo, c, acc[2 * i]);
        acc[2 * i + 1] = fmaf(hi, c, acc[2 * i + 1]);
    }
}

__device__ __forceinline__ void agg_node_bf16(const ushort_t* __restrict__ H,
                                              const int* __restrict__ deg,
                                              const int* __restrict__ col,
                                              const float* __restrict__ dinv,
                                              const float* __restrict__ bias,
                                              int v, int f, float* r) {
    const int beg = v << 6;
    int d = deg[v]; if (d > BKT_CAP) d = BKT_CAP;
    const int end = beg + d;
    const float dv = dinv[v];
    float acc[8] = {};
    int j = beg;
    for (; j + 7 < end; j += 8) {
        int s[8];
#pragma unroll
        for (int u = 0; u < 8; ++u) s[u] = col[j + u];
        float c[8];
#pragma unroll
        for (int u = 0; u < 8; ++u) c[u] = dinv[s[u]] * dv;
        uint4 h[8];
#pragma unroll
        for (int u = 0; u < 8; ++u) h[u] = *(const uint4*)(H + (size_t)s[u] * D_H + f);
#pragma unroll
        for (int u = 0; u < 8; ++u) bf8_fma(h[u], c[u], acc);
    }
    for (; j + 3 < end; j += 4) {
        int s0 = col[j], s1 = col[j + 1], s2 = col[j + 2], s3 = col[j + 3];
        float c0 = dinv[s0] * dv, c1 = dinv[s1] * dv;
        float c2 = dinv[s2] * dv, c3 = dinv[s3] * dv;
        uint4 h0 = *(const uint4*)(H + (size_t)s0 * D_H + f);
        uint4 h1 = *(const uint4*)(H + (size_t)s1 * D_H + f);
        uint4 h2 = *(const uint4*)(H + (size_t)s2 * D_H + f);
        uint4 h3 = *(const uint4*)(H + (size_t)s3 * D_H + f);
        bf8_fma(h0, c0, acc);
        bf8_fma(h1, c1, acc);
        bf8_fma(h2, c2, acc);
        bf8_fma(h3, c3, acc);
    }
    for (; j < end; ++j) {
        int s0 = col[j];
        float c0 = dinv[s0] * dv;
        uint4 h0 = *(const uint4*)(H + (size_t)s0 * D_H + f);
        bf8_fma(h0, c0, acc);
    }
    uint4 hv = *(const uint4*)(H + (size_t)v * D_H + f);
    bf8_fma(hv, dv * dv, acc);  // self-loop
    float4 b0 = *(const float4*)(bias + f);
    float4 b1 = *(const float4*)(bias + f + 4);
    r[0] = fmaxf(acc[0] + b0.x, 0.f);
    r[1] = fmaxf(acc[1] + b0.y, 0.f);
    r[2] = fmaxf(acc[2] + b0.z, 0.f);
    r[3] = fmaxf(acc[3] + b0.w, 0.f);
    r[4] = fmaxf(acc[4] + b1.x, 0.f);
    r[5] = fmaxf(acc[5] + b1.y, 0.f);
    r[6] = fmaxf(acc[6] + b1.z, 0.f);
    r[7] = fmaxf(acc[7] + b1.w, 0.f);
}

// 4 nodes per block (one per wave)
__global__ __launch_bounds__(256) void gather_agg_relu_bf16(const ushort_t* __restrict__ H,
                                                            const int* __restrict__ deg,
                                                            const int* __restrict__ col,
                                                            const float* __restrict__ dinv,
                                                            const float* __restrict__ bias,
                                                            ushort_t* __restrict__ out) {
    const int v = blockIdx.x * 4 + (threadIdx.x >> 6);
    const int f = (threadIdx.x & 63) * 8;
    float r[8];
    agg_node_bf16(H, deg, col, dinv, bias, v, f, r);
    ushort_t o[8];
#pragma unroll
    for (int i = 0; i < 8; ++i) o[i] = f2b(r[i]);
    *(uint4*)(out + (size_t)v * D_H + f) = *(uint4*)o;
}

// ---------------- segment max pool: node-split partial + reduce ----------------
__global__ __launch_bounds__(256) void pool_max_partial(const ushort_t* __restrict__ h2,
                                                        const int* __restrict__ gstart,
                                                        float* __restrict__ pbuf) {
    const int g = blockIdx.x;
    const int s = blockIdx.y;
    const int f = threadIdx.x * 2;
    const int beg = gstart[g], end = gstart[g + 1];
    const int len = end - beg;
    const int chunk = (len + PSPLIT - 1) / PSPLIT;
    int lo = beg + s * chunk;
    int hi = lo + chunk; if (hi > end) hi = end;
    float m0 = -INFINITY, m1 = -INFINITY;
    int v = lo;
    for (; v + 3 < hi; v += 4) {
        unsigned u0 = *(const unsigned*)(h2 + (size_t)(v + 0) * D_H + f);
        unsigned u1 = *(const unsigned*)(h2 + (size_t)(v + 1) * D_H + f);
        unsigned u2 = *(const unsigned*)(h2 + (size_t)(v + 2) * D_H + f);
        unsigned u3 = *(const unsigned*)(h2 + (size_t)(v + 3) * D_H + f);
        m0 = fmaxf(m0, fmaxf(fmaxf(__uint_as_float(u0 << 16), __uint_as_float(u1 << 16)),
                             fmaxf(__uint_as_float(u2 << 16), __uint_as_float(u3 << 16))));
        m1 = fmaxf(m1, fmaxf(fmaxf(__uint_as_float(u0 & 0xFFFF0000u), __uint_as_float(u1 & 0xFFFF0000u)),
                             fmaxf(__uint_as_float(u2 & 0xFFFF0000u), __uint_as_float(u3 & 0xFFFF0000u))));
    }
    for (; v < hi; ++v) {
        unsigned u = *(const unsigned*)(h2 + (size_t)v * D_H + f);
        m0 = fmaxf(m0, __uint_as_float(u << 16));
        m1 = fmaxf(m1, __uint_as_float(u & 0xFFFF0000u));
    }
    float* p = pbuf + ((size_t)s * N_GRAPHS + g) * D_H + f;
    p[0] = m0;
    p[1] = m1;
}

__global__ void pool_max_final(const float* __restrict__ pbuf, float* __restrict__ gbuf) {
    int i = blockIdx.x * blockDim.x + threadIdx.x;
    if (i >= N_GRAPHS * D_H) return;
    float m = -INFINITY;
#pragma unroll
    for (int s = 0; s < PSPLIT; ++s) m = fmaxf(m, pbuf[(size_t)s * N_GRAPHS * D_H + i]);
    gbuf[i] = m;
}

extern "C" void kernel_launch(void* const* d_in, const int* in_sizes, int n_in,
                              void* d_out, int out_size, void* d_ws, size_t ws_size,
                              hipStream_t stream) {
    const float* x     = (const float*)d_in[0];
    const int*   ei    = (const int*)d_in[1];
    const int*   batch = (const int*)d_in[2];
    const float* Wg1   = (const float*)d_in[3];
    const float* bg1   = (const float*)d_in[4];
    const float* Wg2   = (const float*)d_in[5];
    const float* bg2   = (const float*)d_in[6];
    const float* W1    = (const float*)d_in[7];
    const float* b1    = (const float*)d_in[8];
    const float* W2    = (const float*)d_in[9];
    const float* b2    = (const float*)d_in[10];
    const float* gamma = (const float*)d_in[11];
    const float* beta  = (const float*)d_in[12];
    const int* src = ei;
    const int* dst = ei + N_EDGES;
    float* out = (float*)d_out;

    const int S1 = 8;  // fc1 K-split
    const int S2 = 8;  // fc2 K-split

    // workspace layout (16B-aligned)
    ushort_t* hpre   = (ushort_t*)d_ws;                        // [N_NODES, D_H] bf16
    ushort_t* h1b    = hpre + (size_t)N_NODES * D_H;           // [N_NODES, D_H] bf16
    ushort_t* w1t    = h1b + (size_t)N_NODES * D_H;            // [D_H, D_IN] bf16
    ushort_t* w2t    = w1t + (size_t)D_H * D_IN;               // [D_H, D_H] bf16
    float*    dinv   = (float*)(w2t + (size_t)D_H * D_H);      // [N_NODES]
    float*    gbuf   = dinv + N_NODES;                         // [N_GRAPHS, D_H]
    float*    pbuf   = gbuf + N_GRAPHS * D_H;                  // [PSPLIT, N_GRAPHS, D_H]
    float*    fc1o   = pbuf + (size_t)PSPLIT * N_GRAPHS * D_H; // [N_GRAPHS, D_FC]
    float*    part1  = fc1o + N_GRAPHS * D_FC;                 // [S1, 64, D_FC]
    float*    part2  = part1 + (size_t)S1 * N_GRAPHS * D_FC;   // [S2, 64, OUT_DIMS]
    int*      cursor = (int*)(part2 + (size_t)S2 * N_GRAPHS * OUT_DIMS);  // [N_NODES] -> degree
    int*      colbkt = cursor + N_NODES;                       // [N_NODES * BKT_CAP]
    int*      gstart = colbkt + (size_t)N_NODES * BKT_CAP;     // [N_GRAPHS+1]

    // ---- fused prep: zero cursor + W1^T + W2^T + graph bounds ----
    prep_all<<<PREP_NBLK, 256, 0, stream>>>(Wg1, w1t, Wg2, w2t, cursor, batch, gstart);

    // ---- bucket adjacency build ----
    fill_bucket<<<(N_EDGES + 255) / 256, 256, 0, stream>>>(src, dst, cursor, colbkt);
    compute_dinv<<<(N_NODES + 255) / 256, 256, 0, stream>>>(cursor, dinv);

    dim3 gconv(32, 20);  // 640 slots, 628 active (157 row-tiles x 4 col-tiles)

    // conv1: hpre = bf16(x @ Wg1), A consumed as f32 in-kernel ; gather+relu -> h1b
    mfma_gemm_af32<<<gconv, 256, 0, stream>>>(x, w1t, hpre, N_NODES, D_H, D_IN);
    gather_agg_relu_bf16<<<N_NODES / 4, 256, 0, stream>>>(hpre, cursor, colbkt, dinv, bg1, h1b);

    // conv2: hpre = bf16(h1b @ Wg2) ; gather+relu -> h2 (reuse h1b) ; pool
    mfma_gemm_db<<<gconv, 256, 0, stream>>>(h1b, w2t, hpre, N_NODES, D_H, D_H);
    gather_agg_relu_bf16<<<N_NODES / 4, 256, 0, stream>>>(hpre, cursor, colbkt, dinv, bg2, h1b);
    pool_max_partial<<<dim3(N_GRAPHS, PSPLIT), 256, 0, stream>>>(h1b, gstart, pbuf);
    pool_max_final<<<(N_GRAPHS * D_H + 255) / 256, 256, 0, stream>>>(pbuf, gbuf);

    // fc1: [64,512]@[512,1024] split-K=8 -> part1 ; reduce + b1 + relu -> fc1o
    dim3 gfc1((D_FC + 63) / 64, 1, S1);
    gemm_splitk<<<gfc1, 256, 0, stream>>>(gbuf, W1, part1, N_GRAPHS, D_FC, D_H, D_H / S1);
    reduce_bias_relu<<<(N_GRAPHS * D_FC + 255) / 256, 256, 0, stream>>>(
        part1, b1, fc1o, N_GRAPHS * D_FC, D_FC, S1);

    // fc2: [64,1024]@[1024,5000] split-K=8 -> part2 ; reduce + BN + sigmoid -> out
    dim3 gfc2((OUT_DIMS + 63) / 64, 1, S2);
    gemm_splitk<<<gfc2, 256, 0, stream>>>(fc1o, W2, part2, N_GRAPHS, OUT_DIMS, D_FC, D_FC / S2);
    reduce_bn_sigmoid<<<(N_GRAPHS * OUT_DIMS + 255) / 256, 256, 0, stream>>>(
        part2, b2, gamma, beta, out, S2);
}